// Round 1
// baseline (107.403 us; speedup 1.0000x reference)
//
#include <hip/hip_runtime.h>
#include <math.h>

// out[b] = (1^T · Π_d C_d · P) · Π_d x[b,d] + bias — per-row scalars commute
// out of the batch-independent matrix chain. Two kernels (round-6 structure,
// verified 113.5 us; rounds 7/8 proved intra-kernel producer/consumer fusion
// thrashes the scheduler/L2 on this grid):
//   mps_chain (32 blocks): fold 64-core chunks. NEW: wave-parallel tree fold
//     — each of 4 waves folds 16 matrices privately (4 elems/lane, per-wave
//     LDS ping-pong, wave-synchronous, no barriers), wave 0 combines with 3
//     multiplies. Critical path 64 barriered steps -> 15+3 unbarriered.
//     Fan-in via flags; block 0 reduces 32 partials in wave-0 registers,
//     projects -> pE (verbatim round 6).
//   mps_rows (2048 blocks): compulsory ~64 MB read, one wave/row (verbatim).
// Row products underflow fp32 to 0 exactly as the reference (absmax 0.0,
// verified rounds 1/5/6).

#define DFEAT 2048
#define R 16
#define NR2 256               // R*R
#define OUTD 64
#define CHUNK 64              // cores folded per chain block
#define NCHUNK (DFEAT / CHUNK)    // 32 chain blocks
#define MAGIC 0x7E57C0DE

// (Arow · B)[c0..c0+3]: Arow = 16 LDS floats (4x ds_read_b128), B = 16x16
// row-major LDS matrix. All FMA, no barriers.
__device__ __forceinline__ float4 rowmul(const float* Arow, const float* B,
                                         int c0) {
    float4 acc = {0.f, 0.f, 0.f, 0.f};
    const float4* a4 = (const float4*)Arow;
#pragma unroll
    for (int kk = 0; kk < 4; ++kk) {
        const float4 av = a4[kk];
        const float4 b0 = *(const float4*)&B[(4 * kk + 0) * 16 + c0];
        const float4 b1 = *(const float4*)&B[(4 * kk + 1) * 16 + c0];
        const float4 b2 = *(const float4*)&B[(4 * kk + 2) * 16 + c0];
        const float4 b3 = *(const float4*)&B[(4 * kk + 3) * 16 + c0];
        acc.x = fmaf(av.x, b0.x, fmaf(av.y, b1.x, fmaf(av.z, b2.x, fmaf(av.w, b3.x, acc.x))));
        acc.y = fmaf(av.x, b0.y, fmaf(av.y, b1.y, fmaf(av.z, b2.y, fmaf(av.w, b3.y, acc.y))));
        acc.z = fmaf(av.x, b0.z, fmaf(av.y, b1.z, fmaf(av.z, b2.z, fmaf(av.w, b3.z, acc.z))));
        acc.w = fmaf(av.x, b0.w, fmaf(av.y, b1.w, fmaf(av.z, b2.w, fmaf(av.w, b3.w, acc.w))));
    }
    return acc;
}

__global__ __launch_bounds__(256) void mps_chain(const float* __restrict__ cores,
                                                 const float* __restrict__ proj,
                                                 float* __restrict__ partials,
                                                 int* __restrict__ flags,
                                                 float* __restrict__ pE) {
    __shared__ __align__(16) float Cs[CHUNK * NR2];     // 64 KB staged cores
    __shared__ __align__(16) float Aw[4][2][NR2];       // 8 KB per-wave pp
    __shared__ __align__(16) float F[2][NR2];           // 2 KB combine pp
    __shared__ __align__(16) float Pt[NCHUNK * NR2];    // 32 KB transposed
    const int tid  = threadIdx.x;
    const int wave = tid >> 6, lane = tid & 63;
    const int ri = lane >> 2;             // row 0..15 (this lane's A/F row)
    const int c0 = (lane & 3) << 2;       // col base 0,4,8,12
    const size_t d0 = (size_t)blockIdx.x * CHUNK;

    // ---- stage all 64 cores: 4096 float4, 16/thread, coalesced ----
    const float4* g4 = (const float4*)(cores + d0 * NR2);
    float4* s4 = (float4*)&Cs[0];
#pragma unroll
    for (int q = 0; q < 16; ++q)
        s4[q * 256 + tid] = g4[q * 256 + tid];
    __syncthreads();

    // ---- per-wave fold of 16 matrices, wave-synchronous (no barriers) ----
    // (within-wave ds_write -> ds_read ordering via lgkmcnt; lockstep wave64)
    *(float4*)&Aw[wave][0][ri * 16 + c0] =
        *(const float4*)&Cs[(16 * wave) * NR2 + ri * 16 + c0];
    int cur = 0;
    for (int t = 1; t < 16; ++t) {        // 15 multiplies -> result in buf 1
        float4 r = rowmul(&Aw[wave][cur][ri * 16],
                          &Cs[(16 * wave + t) * NR2], c0);
        *(float4*)&Aw[wave][cur ^ 1][ri * 16 + c0] = r;
        cur ^= 1;
    }
    __syncthreads();                      // all 4 wave-products ready

    // ---- wave 0 combines: F = Aw0 x Aw1 x Aw2 x Aw3 (3 multiplies) ----
    if (wave == 0) {
        *(float4*)&F[0][ri * 16 + c0] =
            *(const float4*)&Aw[0][1][ri * 16 + c0];
        int cc = 0;
        for (int w = 1; w < 4; ++w) {     // 3 multiplies -> result in F[1]
            float4 r = rowmul(&F[cc][ri * 16], &Aw[w][1][0], c0);
            *(float4*)&F[cc ^ 1][ri * 16 + c0] = r;
            cc ^= 1;
        }
    }
    __syncthreads();
    const int i = tid >> 4, j = tid & 15;
    const float v = F[1][tid];            // element (i,j) of chunk product

    if (blockIdx.x != 0) {
        // ---- producer: publish partial, release flag (verbatim round 6) ----
        partials[blockIdx.x * NR2 + tid] = v;
        __syncthreads();                  // block stores complete at L2
        if (tid == 0)
            __hip_atomic_store(&flags[blockIdx.x], MAGIC,
                               __ATOMIC_RELEASE, __HIP_MEMORY_SCOPE_AGENT);
        return;
    }

    // ---- block 0: own partial straight into LDS (transposed) ----
    Pt[0 * 256 + j * 16 + i] = v;

    // acquire-spin for producers 1..31 (every thread: cache-inv side effect)
    {
        const int f = 1 + (tid % (NCHUNK - 1));
        while (__hip_atomic_load(&flags[f], __ATOMIC_ACQUIRE,
                                 __HIP_MEMORY_SCOPE_AGENT) != MAGIC) { }
    }
    __syncthreads();

    // ---- stage partials 1..31 into LDS transposed: 1984 float4 coalesced ---
#pragma unroll
    for (int q = 0; q < 8; ++q) {
        const int idx = q * 256 + tid;                // float4 index
        if (idx < (NCHUNK - 1) * 64) {
            float4 p4 = ((const float4*)(partials + NR2))[idx];
            const int flat = idx * 4;
            const int gg = (flat >> 8) + 1;           // which partial (1..31)
            const int e = flat & 255;
            const int k = e >> 4, j0 = e & 15;        // row k, cols j0..j0+3
            Pt[gg * 256 + (j0 + 0) * 16 + k] = p4.x;
            Pt[gg * 256 + (j0 + 1) * 16 + k] = p4.y;
            Pt[gg * 256 + (j0 + 2) * 16 + k] = p4.z;
            Pt[gg * 256 + (j0 + 3) * 16 + k] = p4.w;
        }
    }
    __syncthreads();

    // ---- wave-0 register fold: w <- w @ P_g, g = 0..31 (verbatim rd 6) ----
    if (tid < 64) {
        const int jj = tid & 15, q = tid >> 4;        // lane = jj + 16*q
        float w = 1.f;                                // w[jj], replicated in q
        int E = 0;
        for (int gg = 0; gg < NCHUNK; ++gg) {
            const float4 pr = *(const float4*)&Pt[gg * 256 + jj * 16 + 4 * q];
            float s;
            s = __shfl(w, 4 * q + 0) * pr.x;          // w[k] lives at lane k
            s = fmaf(__shfl(w, 4 * q + 1), pr.y, s);
            s = fmaf(__shfl(w, 4 * q + 2), pr.z, s);
            s = fmaf(__shfl(w, 4 * q + 3), pr.w, s);
            s += __shfl_xor(s, 16);                   // sum the 4 q-groups
            s += __shfl_xor(s, 32);                   // -> nw[jj], replicated
            w = s;
            if ((gg & 7) == 7) {                      // exact pow2 renorm
                float m = fabsf(w);
#pragma unroll
                for (int off = 1; off <= 8; off <<= 1)
                    m = fmaxf(m, __shfl_xor(m, off));
                if (m > 0.f) {
                    int e = 0;
                    (void)frexpf(m, &e);              // m = f*2^e, f in [.5,1)
                    w = ldexpf(w, -e);                // exact rescale
                    E += e;
                }
            }
        }
        // p[o] = sum_k w[k] * proj[k][o]
        float p = 0.f;
#pragma unroll
        for (int k = 0; k < R; ++k)
            p = fmaf(__shfl(w, k), proj[k * OUTD + tid], p);
        pE[tid] = p;
        if (tid == 0) ((int*)pE)[OUTD] = E;
    }
}

// ---------------------------------------------------------------------------
// One wave per batch row (verbatim rounds 5/6; at the memory roofline).
// ---------------------------------------------------------------------------
__global__ __launch_bounds__(256) void mps_rows(const float* __restrict__ x,
                                                const float* __restrict__ pE,
                                                const float* __restrict__ bias,
                                                float* __restrict__ out,
                                                int B) {
    const int gtid = blockIdx.x * 256 + threadIdx.x;
    const int row  = gtid >> 6;           // wave id == row
    const int lane = threadIdx.x & 63;
    if (row >= B) return;

    const float4* xr = (const float4*)(x + (size_t)row * DFEAT);
    float prod = 1.f;
#pragma unroll
    for (int it = 0; it < DFEAT / (64 * 4); ++it) {   // 8 iters, 1 KiB/instr
        float4 v = xr[it * 64 + lane];
        prod *= (v.x * v.y) * (v.z * v.w);
    }
#pragma unroll
    for (int off = 32; off > 0; off >>= 1)            // wave-wide product
        prod *= __shfl_xor(prod, off);

    const float pv = pE[lane];                        // lane < 64 == OUTD
    const int   E  = ((const int*)pE)[OUTD];
    out[(size_t)row * OUTD + lane] = ldexpf(pv * prod, E) + bias[lane];
}

// ---------------------------------------------------------------------------
extern "C" void kernel_launch(void* const* d_in, const int* in_sizes, int n_in,
                              void* d_out, int out_size, void* d_ws, size_t ws_size,
                              hipStream_t stream) {
    const float* inputs = (const float*)d_in[0];   // (B, 2048) fp32
    const float* cores  = (const float*)d_in[1];   // (2048, 16, 16) fp32
    const float* proj   = (const float*)d_in[2];   // (16, 64) fp32
    const float* bias   = (const float*)d_in[3];   // (64,) fp32
    float* out = (float*)d_out;                    // (B, 64) fp32

    // ws layout (16B aligned): partials | pE (64f + int E, padded) | flags
    float* partials = (float*)d_ws;                // 32*256 floats (32 KiB)
    float* pE    = partials + NCHUNK * NR2;        // 64 floats + int E (+pad)
    int*   flags = (int*)(pE + 68);                // 32 ints; 0xAA poison
                                                   // != MAGIC each replay

    const int B = in_sizes[0] / DFEAT;             // 8192

    mps_chain<<<NCHUNK, 256, 0, stream>>>(cores, proj, partials, flags, pE);
    mps_rows<<<(B * 64 + 255) / 256, 256, 0, stream>>>(inputs, pE, bias, out, B);
}

// Round 2
// 105.230 us; speedup vs baseline: 1.0207x; 1.0207x over previous
//
#include <hip/hip_runtime.h>
#include <math.h>

// out[b] = (1^T · Π_d C_d · P) · Π_d x[b,d] + bias — per-row scalars commute
// out of the batch-independent matrix chain.
//
// ROUND 9 (this round): overlap the ~13 us latency-bound chain with the
// ~11 us BW-bound row stream. Structure:
//   mps_fused (32 chain blocks + 2048 row blocks, ONE kernel):
//     - chain blocks: same wave-parallel tree fold as the verified round-8
//       kernel, but LDS cut 106 KB -> 26 KB so row blocks co-reside at
//       6 blocks/CU: cores are reg-prefetched + double-buffered per wave
//       (1 KB ping-pong) instead of a 64 KB Cs stage; block-0's partial
//       fold stages 8 partials/round (4 rounds) instead of a 32 KB Pt.
//       Fan-in flags verbatim. Producers/blk0 logic verbatim.
//     - row blocks: the verified streaming product loop, but they write
//       prod[row] to ws and EXIT — no spin, no pE dependence. Forward
//       progress never depends on residency (the round-7/8 fusion thrash
//       was consumer-spin + churn; this design has no consumer spin).
//   mps_scale (2048 blocks): out = ldexp(pE[o]*prod[b],E)+bias — 2 MB
//       coalesced write, ~1.5 us.
// Row products underflow fp32 to 0 exactly as the reference (absmax 0.0).

#define DFEAT 2048
#define R 16
#define NR2 256               // R*R
#define OUTD 64
#define CHUNK 64              // cores folded per chain block
#define NCHUNK (DFEAT / CHUNK)    // 32 chain blocks
#define MAGIC 0x7E57C0DE

// (Arow · B)[c0..c0+3]: Arow = 16 LDS floats (4x ds_read_b128), B = 16x16
// row-major LDS matrix. All FMA, no barriers. (verbatim)
__device__ __forceinline__ float4 rowmul(const float* Arow, const float* B,
                                         int c0) {
    float4 acc = {0.f, 0.f, 0.f, 0.f};
    const float4* a4 = (const float4*)Arow;
#pragma unroll
    for (int kk = 0; kk < 4; ++kk) {
        const float4 av = a4[kk];
        const float4 b0 = *(const float4*)&B[(4 * kk + 0) * 16 + c0];
        const float4 b1 = *(const float4*)&B[(4 * kk + 1) * 16 + c0];
        const float4 b2 = *(const float4*)&B[(4 * kk + 2) * 16 + c0];
        const float4 b3 = *(const float4*)&B[(4 * kk + 3) * 16 + c0];
        acc.x = fmaf(av.x, b0.x, fmaf(av.y, b1.x, fmaf(av.z, b2.x, fmaf(av.w, b3.x, acc.x))));
        acc.y = fmaf(av.x, b0.y, fmaf(av.y, b1.y, fmaf(av.z, b2.y, fmaf(av.w, b3.y, acc.y))));
        acc.z = fmaf(av.x, b0.z, fmaf(av.y, b1.z, fmaf(av.z, b2.z, fmaf(av.w, b3.z, acc.z))));
        acc.w = fmaf(av.x, b0.w, fmaf(av.y, b1.w, fmaf(av.z, b2.w, fmaf(av.w, b3.w, acc.w))));
    }
    return acc;
}

__global__ __launch_bounds__(256) void mps_fused(const float* __restrict__ cores,
                                                 const float* __restrict__ proj,
                                                 const float* __restrict__ x,
                                                 float* __restrict__ prodbuf,
                                                 float* __restrict__ partials,
                                                 int* __restrict__ flags,
                                                 float* __restrict__ pE,
                                                 int B) {
    // 26 KB total -> 6 blocks/CU (156 KB), 24 waves/CU for the row stream.
    __shared__ __align__(16) float Bb[4][2][NR2];   // 8 KB per-wave core pp
    __shared__ __align__(16) float Aw[4][2][NR2];   // 8 KB per-wave A pp
    __shared__ __align__(16) float F[2][NR2];       // 2 KB combine pp
    __shared__ __align__(16) float Pt[8 * NR2];     // 8 KB partial stage

    const int tid  = threadIdx.x;
    const int wave = tid >> 6, lane = tid & 63;

    if (blockIdx.x >= NCHUNK) {
        // ================= row block: streaming product, no waits ==========
        const int row = (blockIdx.x - NCHUNK) * 4 + wave;
        if (row >= B) return;
        const float4* xr = (const float4*)(x + (size_t)row * DFEAT);
        float prod = 1.f;
#pragma unroll
        for (int it = 0; it < DFEAT / (64 * 4); ++it) {   // 8 iters, 1 KiB/instr
            float4 v = xr[it * 64 + lane];
            prod *= (v.x * v.y) * (v.z * v.w);
        }
#pragma unroll
        for (int off = 32; off > 0; off >>= 1)            // wave-wide product
            prod *= __shfl_xor(prod, off);
        if (lane == 0) prodbuf[row] = prod;
        return;
    }

    // ==================== chain block (blockIdx.x < 32) =====================
    const int ri = lane >> 2;             // row 0..15 (this lane's A/F row)
    const int c0 = (lane & 3) << 2;       // col base 0,4,8,12
    const size_t d0 = (size_t)blockIdx.x * CHUNK;

    // ---- per-wave fold of 16 matrices, wave-synchronous (no barriers) ----
    // Cores reg-prefetched one ahead, double-buffered in 1 KB LDS ping-pong.
    // (lane*4 floats == ri*16 + c0, so the coalesced float4 load per lane
    //  lands exactly at this lane's (ri, c0..c0+3) slot.)
    const float* gw = cores + (d0 + 16 * wave) * NR2;
    *(float4*)&Aw[wave][0][lane * 4] = *(const float4*)&gw[lane * 4];  // A=core0
    float4 nxt = *(const float4*)&gw[NR2 + lane * 4];                  // core1
    int cur = 0;
    for (int t = 1; t < 16; ++t) {        // 15 multiplies -> result in buf 1
        *(float4*)&Bb[wave][t & 1][lane * 4] = nxt;    // stash core t
        if (t < 15)                                    // prefetch core t+1
            nxt = *(const float4*)&gw[(size_t)(t + 1) * NR2 + lane * 4];
        float4 r = rowmul(&Aw[wave][cur][ri * 16], &Bb[wave][t & 1][0], c0);
        *(float4*)&Aw[wave][cur ^ 1][ri * 16 + c0] = r;
        cur ^= 1;
    }
    __syncthreads();                      // all 4 wave-products ready

    // ---- wave 0 combines: F = Aw0 x Aw1 x Aw2 x Aw3 (3 multiplies) ----
    if (wave == 0) {
        *(float4*)&F[0][ri * 16 + c0] =
            *(const float4*)&Aw[0][1][ri * 16 + c0];
        int cc = 0;
        for (int w = 1; w < 4; ++w) {     // 3 multiplies -> result in F[1]
            float4 r = rowmul(&F[cc][ri * 16], &Aw[w][1][0], c0);
            *(float4*)&F[cc ^ 1][ri * 16 + c0] = r;
            cc ^= 1;
        }
    }
    __syncthreads();
    const int i = tid >> 4, j = tid & 15;
    const float v = F[1][tid];            // element (i,j) of chunk product

    if (blockIdx.x != 0) {
        // ---- producer: publish partial, release flag (verbatim) ----
        partials[blockIdx.x * NR2 + tid] = v;
        __syncthreads();                  // block stores complete at L2
        if (tid == 0)
            __hip_atomic_store(&flags[blockIdx.x], MAGIC,
                               __ATOMIC_RELEASE, __HIP_MEMORY_SCOPE_AGENT);
        return;
    }

    // ---- block 0: own partial straight into LDS slot 0 (transposed) ----
    Pt[0 * 256 + j * 16 + i] = v;

    // acquire-spin for producers 1..31 (every thread: cache-inv side effect)
    {
        const int f = 1 + (tid % (NCHUNK - 1));
        while (__hip_atomic_load(&flags[f], __ATOMIC_ACQUIRE,
                                 __HIP_MEMORY_SCOPE_AGENT) != MAGIC) { }
    }
    __syncthreads();

    // ---- 4 rounds: stage 8 partials transposed (8 KB) + wave-0 fold ----
    float w = 1.f;                        // fold state lives in wave-0 regs
    int E = 0;
    for (int rr = 0; rr < 4; ++rr) {
#pragma unroll
        for (int q = 0; q < 2; ++q) {                 // 512 float4 / round
            const int idx = q * 256 + tid;
            const int flat = idx * 4;
            const int s = flat >> 8;                  // local slot 0..7
            if (rr > 0 || s > 0) {                    // slot 0 of rr=0 = own
                float4 p4 =
                    ((const float4*)(partials + (size_t)(8 * rr) * NR2))[idx];
                const int e = flat & 255;
                const int k = e >> 4, j0 = e & 15;    // row k, cols j0..j0+3
                Pt[s * 256 + (j0 + 0) * 16 + k] = p4.x;
                Pt[s * 256 + (j0 + 1) * 16 + k] = p4.y;
                Pt[s * 256 + (j0 + 2) * 16 + k] = p4.z;
                Pt[s * 256 + (j0 + 3) * 16 + k] = p4.w;
            }
        }
        __syncthreads();
        if (tid < 64) {                   // wave-0 register fold, 8 per round
            const int jj = tid & 15, q = tid >> 4;    // lane = jj + 16*q
            for (int s = 0; s < 8; ++s) {
                const float4 pr = *(const float4*)&Pt[s * 256 + jj * 16 + 4 * q];
                float sum;
                sum = __shfl(w, 4 * q + 0) * pr.x;    // w[k] lives at lane k
                sum = fmaf(__shfl(w, 4 * q + 1), pr.y, sum);
                sum = fmaf(__shfl(w, 4 * q + 2), pr.z, sum);
                sum = fmaf(__shfl(w, 4 * q + 3), pr.w, sum);
                sum += __shfl_xor(sum, 16);           // sum the 4 q-groups
                sum += __shfl_xor(sum, 32);           // -> nw[jj], replicated
                w = sum;
            }
            // renorm once per round (global gg = 8*rr+7 -> gg&7==7, as before)
            float m = fabsf(w);
#pragma unroll
            for (int off = 1; off <= 8; off <<= 1)
                m = fmaxf(m, __shfl_xor(m, off));
            if (m > 0.f) {
                int e2 = 0;
                (void)frexpf(m, &e2);                 // m = f*2^e, f in [.5,1)
                w = ldexpf(w, -e2);                   // exact rescale
                E += e2;
            }
        }
        __syncthreads();                  // Pt reusable next round
    }

    if (tid < 64) {
        // p[o] = sum_k w[k] * proj[k][o]
        float p = 0.f;
#pragma unroll
        for (int k = 0; k < R; ++k)
            p = fmaf(__shfl(w, k), proj[k * OUTD + tid], p);
        pE[tid] = p;
        if (tid == 0) ((int*)pE)[OUTD] = E;
    }
}

// ---------------------------------------------------------------------------
// Epilogue: out[b][o] = ldexp(pE[o] * prod[b], E) + bias[o]. 2 MB coalesced.
// ---------------------------------------------------------------------------
__global__ __launch_bounds__(256) void mps_scale(const float* __restrict__ prodbuf,
                                                 const float* __restrict__ pE,
                                                 const float* __restrict__ bias,
                                                 float* __restrict__ out,
                                                 int B) {
    const int gtid = blockIdx.x * 256 + threadIdx.x;
    const int row  = gtid >> 6;
    const int lane = threadIdx.x & 63;
    if (row >= B) return;
    const float pv = pE[lane];                        // lane < 64 == OUTD
    const int   E  = ((const int*)pE)[OUTD];
    out[(size_t)row * OUTD + lane] = ldexpf(pv * prodbuf[row], E) + bias[lane];
}

// ---------------------------------------------------------------------------
extern "C" void kernel_launch(void* const* d_in, const int* in_sizes, int n_in,
                              void* d_out, int out_size, void* d_ws, size_t ws_size,
                              hipStream_t stream) {
    const float* inputs = (const float*)d_in[0];   // (B, 2048) fp32
    const float* cores  = (const float*)d_in[1];   // (2048, 16, 16) fp32
    const float* proj   = (const float*)d_in[2];   // (16, 64) fp32
    const float* bias   = (const float*)d_in[3];   // (64,) fp32
    float* out = (float*)d_out;                    // (B, 64) fp32

    const int B = in_sizes[0] / DFEAT;             // 8192

    // ws layout (16B aligned): prodbuf | partials | pE (64f + E) | flags
    float* prodbuf  = (float*)d_ws;                // B floats (32 KiB)
    float* partials = prodbuf + B;                 // 32*256 floats (32 KiB)
    float* pE    = partials + NCHUNK * NR2;        // 64 floats + int E (+pad)
    int*   flags = (int*)(pE + 68);                // 32 ints; harness poison
                                                   // != MAGIC each replay

    const int rowBlocks = (B + 3) / 4;             // 4 rows (waves) per block
    mps_fused<<<NCHUNK + rowBlocks, 256, 0, stream>>>(cores, proj, inputs,
                                                      prodbuf, partials, flags,
                                                      pE, B);
    mps_scale<<<(B * 64 + 255) / 256, 256, 0, stream>>>(prodbuf, pE, bias,
                                                        out, B);
}